// Round 13
// baseline (82.476 us; speedup 1.0000x reference)
//
#include <hip/hip_runtime.h>
#include <math.h>

#define EPSF 1e-5f

constexpr int B_ = 2, C_ = 256, H_ = 56, W_ = 56, N_ = 3136;
constexpr int MID_ = 32, L_ = 112, IN_ = 64, NH_ = 8;

typedef __attribute__((ext_vector_type(8))) __bf16 bf16x8;
typedef __attribute__((ext_vector_type(16))) float f32x16;

// workspace offsets (in floats; all multiples of 4 for 16B alignment)
constexpr size_t O_POOL = 0;
constexpr size_t O_GH   = O_POOL + (size_t)B_*C_*L_;             // ghT [b][H][C]
constexpr size_t O_GW   = O_GH   + (size_t)B_*C_*H_;             // gwT [b][W][C]
constexpr size_t O_QT   = O_GW   + (size_t)B_*C_*W_;             // bf16 [16bh][N][16]
constexpr size_t O_KT   = O_QT   + (size_t)B_*NH_*N_*16/2;
constexpr size_t O_VT   = O_KT   + (size_t)B_*NH_*N_*16/2;       // bf16 [16bh][16][N]
constexpr size_t O_VZ   = O_VT   + (size_t)B_*NH_*16*N_/2;       // bf16 zero row [N]
constexpr size_t O_OUTC = O_VZ   + N_/2;                          // bf16 [B][C][N]
constexpr size_t O_GST  = O_OUTC + (size_t)B_*C_*N_/2;           // fp32 [b*32+g][2] = {S, SS}
constexpr size_t O_PART = O_GST  + (size_t)B_*32*2;              // fp32 [2half][16bh][2g][5][N]
constexpr size_t PART_SZ = (size_t)2*16*2*5*N_;                  // 1,003,520 floats

__device__ inline unsigned pkbf(float lo, float hi) {
  __bf16 a = (__bf16)lo, c = (__bf16)hi;
  return (unsigned)__builtin_bit_cast(unsigned short, a)
       | ((unsigned)__builtin_bit_cast(unsigned short, c) << 16);
}

__device__ inline float bf2f(unsigned short u) {
  unsigned v = (unsigned)u << 16;
  return __builtin_bit_cast(float, v);
}

__device__ inline float fast_exp2(float x) {
#if __has_builtin(__builtin_amdgcn_exp2f)
  return __builtin_amdgcn_exp2f(x);
#else
  float r; asm("v_exp_f32 %0, %1" : "=v"(r) : "v"(x)); return r;
#endif
}

__device__ inline void plane32_swap(unsigned &a, unsigned &b) {
#if __has_builtin(__builtin_amdgcn_permlane32_swap)
  typedef unsigned uv2 __attribute__((ext_vector_type(2)));
  uv2 r = __builtin_amdgcn_permlane32_swap(a, b, false, false);
  a = r.x; b = r.y;
#else
  asm volatile("v_permlane32_swap_b32 %0, %1" : "+v"(a), "+v"(b));
#endif
}

// K1: h_pool / w_pool. one block per (b,c). Also zeroes part_g (needed by attn atomics,
// 3 kernels downstream - plenty of slack).
__global__ __launch_bounds__(256) void k_pool(const float* __restrict__ x, float* __restrict__ pool,
                                              float* __restrict__ part_g) {
  int bc = blockIdx.x;
  // zero part_g: 250,880 uint4 over 512 blocks x 256 threads
  {
    uint4* pg4 = reinterpret_cast<uint4*>(part_g);
    unsigned total = (unsigned)(PART_SZ / 4);
    for (unsigned i = bc*256u + threadIdx.x; i < total; i += 512u*256u)
      pg4[i] = make_uint4(0u, 0u, 0u, 0u);
  }
  const float4* xp4 = reinterpret_cast<const float4*>(x + (size_t)bc * N_);
  __shared__ float tile[N_];
  float4* t4 = reinterpret_cast<float4*>(tile);
  for (int i = threadIdx.x; i < N_/4; i += 256) t4[i] = xp4[i];
  __syncthreads();
  int t = threadIdx.x;
  if (t < 224) {
    int o = t >> 1, half = t & 1;
    float r = 0.f;
    if (o < 56) {
      const float* row = tile + o*W_ + half*28;
      #pragma unroll 7
      for (int j = 0; j < 28; ++j) r += row[j];
    } else {
      const float* col = tile + (half*28)*W_ + (o - 56);
      #pragma unroll 7
      for (int j = 0; j < 28; ++j) r += col[j*W_];
    }
    r += __shfl_xor(r, 1);
    if (half == 0) pool[(size_t)bc*L_ + o] = r * (1.f/56.f);
  }
}

// K3': gates with inline cat recompute. grid = B*H = 112 blocks.
__global__ __launch_bounds__(256) void k_gates2(const float* __restrict__ gcw, const float* __restrict__ pool,
    const float* __restrict__ bng, const float* __restrict__ bnb,
    const float* __restrict__ bnm, const float* __restrict__ bnv,
    const float* __restrict__ ghw, const float* __restrict__ gww,
    float* __restrict__ ghT, float* __restrict__ gwT) {
  int b = blockIdx.x / H_;
  int p = blockIdx.x % H_;
  __shared__ float cat_s[2][MID_];
  int t = threadIdx.x;
  {
    int out = t >> 2, sub = t & 3;
    int m = out & 31, which = out >> 5;
    int l = p + which*H_;
    const float* pp = pool + (size_t)b*C_*L_ + l;
    const float* wp = gcw + (size_t)m*C_ + sub*64;
    float s = 0.f;
    #pragma unroll 16
    for (int c = 0; c < 64; ++c) s += wp[c] * pp[(size_t)(sub*64 + c)*L_];
    s += __shfl_xor(s, 1); s += __shfl_xor(s, 2);
    if (sub == 0) {
      float xn = (s - bnm[m]) * rsqrtf(bnv[m] + EPSF) * bng[m] + bnb[m];
      cat_s[which][m] = xn * fminf(fmaxf(xn + 3.f, 0.f), 6.f) * (1.f/6.f);
    }
  }
  __syncthreads();
  int c = t;
  float sh = 0.f, sw = 0.f;
  #pragma unroll 8
  for (int m = 0; m < MID_; ++m) {
    sh += ghw[c*MID_ + m] * cat_s[0][m];
    sw += gww[c*MID_ + m] * cat_s[1][m];
  }
  ghT[((size_t)b*H_ + p)*C_ + c] = 1.f/(1.f + expf(-sh));
  gwT[((size_t)b*W_ + p)*C_ + c] = 1.f/(1.f + expf(-sw));
}

// K5: fused bias + proj_in GEMM (MFMA) + LayerNorm + QKV GEMM (MFMA) + layout packing.
// Also zeroes gst (block 0).
__global__ __launch_bounds__(256) void k_fused(const float* __restrict__ x,
    const float* __restrict__ piw, const float* __restrict__ lng, const float* __restrict__ lnb,
    const float* __restrict__ wq, const float* __restrict__ wk, const float* __restrict__ wv,
    const float* __restrict__ ghT, const float* __restrict__ gwT,
    unsigned short* __restrict__ qt, unsigned short* __restrict__ kt,
    unsigned short* __restrict__ vt, unsigned short* __restrict__ vz,
    float* __restrict__ gst) {
  __shared__ __align__(16) unsigned short sT[64][72];
  __shared__ float ps[2][2][64][2];
  __shared__ float lg[64], lb[64];
  __shared__ float bias_s[64];
  int b = blockIdx.x / 49, n0 = (blockIdx.x % 49) * 64;
  int tid = threadIdx.x;
  int wv_ = tid >> 6, lane = tid & 63;
  int m = wv_ & 1, nh = wv_ >> 1, l31 = lane & 31, g = lane >> 5;
  int nloc = nh*32 + l31;
  int nglob = n0 + nloc;
  const float QS = 0.35355339059327373f * 1.4426950408889634f;  // scale * log2(e)

  if (tid < 64) { lg[tid] = lng[tid]; lb[tid] = lnb[tid]; }
  if (blockIdx.x == 0 && tid < B_*32*2) gst[tid] = 0.f;

  {
    int px = tid >> 2, sub = tid & 3;
    int n = n0 + px;
    int h = n / W_, w = n % W_;
    const float4* gh4 = reinterpret_cast<const float4*>(ghT + ((size_t)b*H_ + h)*C_ + sub*64);
    const float4* gw4 = reinterpret_cast<const float4*>(gwT + ((size_t)b*W_ + w)*C_ + sub*64);
    float s = 0.f;
    #pragma unroll
    for (int i = 0; i < 16; ++i) {
      float4 a = gh4[i], c2 = gw4[i];
      s += a.x*c2.x + a.y*c2.y + a.z*c2.z + a.w*c2.w;
    }
    s += __shfl_xor(s, 1); s += __shfl_xor(s, 2);
    if (sub == 0)
      bias_s[px] = fmaxf(logf(s * (1.f/C_)), -5.f) * 1.4426950408889634f;
  }
  __syncthreads();

  for (int u = tid; u < 512; u += 256) {
    int h = u >> 6, n = u & 63;
    size_t base = ((size_t)(b*NH_ + h)*N_ + n0 + n)*16;
    *reinterpret_cast<uint4*>(qt + base + 8) = make_uint4(0x3F803F80u, 0u, 0u, 0u);
    float bv = bias_s[n];
    __bf16 bhi = (__bf16)bv; float blo = bv - (float)bhi;
    *reinterpret_cast<uint4*>(kt + base + 8) = make_uint4(pkbf((float)bhi, blo), 0u, 0u, 0u);
  }
  for (int u = tid; u < 512; u += 256) {
    int rr = u >> 3, chunk = u & 7;
    int h = rr >> 3, r = 8 + (rr & 7);
    unsigned val = (r == 8 || r == 12) ? 0x3F803F80u : 0u;
    *reinterpret_cast<uint4*>(vt + ((size_t)(b*NH_+h)*16 + r)*N_ + n0 + chunk*8)
        = make_uint4(val, val, val, val);
  }
  if (b == 0 && tid < 8)
    *reinterpret_cast<uint4*>(vz + n0 + tid*8) = make_uint4(0u, 0u, 0u, 0u);

  // GEMM1: seq_pre[i][n] = sum_c piw[i][c] * x[b][c][n]
  const float* arow = piw + (size_t)(32*m + l31)*C_;
  const float* xcol = x + (size_t)b*C_*N_ + nglob;
  f32x16 acc;
  #pragma unroll
  for (int i = 0; i < 16; ++i) acc[i] = 0.f;
  #pragma unroll 4
  for (int kk = 0; kk < 16; ++kk) {
    const float4* ap = reinterpret_cast<const float4*>(arow + kk*16 + g*8);
    float4 a0 = ap[0], a1 = ap[1];
    uint4 au;
    au.x = pkbf(a0.x, a0.y); au.y = pkbf(a0.z, a0.w);
    au.z = pkbf(a1.x, a1.y); au.w = pkbf(a1.z, a1.w);
    float bvl[8];
    #pragma unroll
    for (int e = 0; e < 8; ++e) bvl[e] = xcol[(size_t)(kk*16 + g*8 + e)*N_];
    uint4 bu;
    bu.x = pkbf(bvl[0], bvl[1]); bu.y = pkbf(bvl[2], bvl[3]);
    bu.z = pkbf(bvl[4], bvl[5]); bu.w = pkbf(bvl[6], bvl[7]);
    acc = __builtin_amdgcn_mfma_f32_32x32x16_bf16(
        __builtin_bit_cast(bf16x8, au), __builtin_bit_cast(bf16x8, bu), acc, 0, 0, 0);
  }

  float s = 0.f, ss = 0.f;
  #pragma unroll
  for (int i = 0; i < 16; ++i) { s += acc[i]; ss += acc[i]*acc[i]; }
  ps[m][g][nloc][0] = s; ps[m][g][nloc][1] = ss;
  __syncthreads();
  float S  = ps[0][0][nloc][0] + ps[0][1][nloc][0] + ps[1][0][nloc][0] + ps[1][1][nloc][0];
  float SS = ps[0][0][nloc][1] + ps[0][1][nloc][1] + ps[1][0][nloc][1] + ps[1][1][nloc][1];
  float mu = S * (1.f/IN_);
  float var = SS * (1.f/IN_) - mu*mu;
  float rsd = rsqrtf(var + EPSF);

  #pragma unroll
  for (int cg = 0; cg < 4; ++cg) {
    int jb = 8*cg + 4*g + 32*m;
    float v0 = (acc[cg*4+0]-mu)*rsd*lg[jb+0] + lb[jb+0];
    float v1 = (acc[cg*4+1]-mu)*rsd*lg[jb+1] + lb[jb+1];
    float v2 = (acc[cg*4+2]-mu)*rsd*lg[jb+2] + lb[jb+2];
    float v3 = (acc[cg*4+3]-mu)*rsd*lg[jb+3] + lb[jb+3];
    uint2 w; w.x = pkbf(v0, v1); w.y = pkbf(v2, v3);
    *reinterpret_cast<uint2*>(&sT[nloc][jb]) = w;
  }
  __syncthreads();

  // GEMM2: q/k/v[i][n] = sum_j w[i][j] * seq[n][j]
  f32x16 aq, ak, av;
  #pragma unroll
  for (int i = 0; i < 16; ++i) { aq[i] = 0.f; ak[i] = 0.f; av[i] = 0.f; }
  const float* qrw = wq + (size_t)(32*m + l31)*IN_;
  const float* krw = wk + (size_t)(32*m + l31)*IN_;
  const float* vrw = wv + (size_t)(32*m + l31)*IN_;
  #pragma unroll
  for (int kk = 0; kk < 4; ++kk) {
    bf16x8 bfr = __builtin_bit_cast(bf16x8,
        *reinterpret_cast<const uint4*>(&sT[nloc][kk*16 + g*8]));
    auto ldA = [&](const float* wrow) {
      const float4* fp = reinterpret_cast<const float4*>(wrow + kk*16 + g*8);
      float4 f0 = fp[0], f1 = fp[1];
      uint4 u;
      u.x = pkbf(f0.x, f0.y); u.y = pkbf(f0.z, f0.w);
      u.z = pkbf(f1.x, f1.y); u.w = pkbf(f1.z, f1.w);
      return __builtin_bit_cast(bf16x8, u);
    };
    aq = __builtin_amdgcn_mfma_f32_32x32x16_bf16(ldA(qrw), bfr, aq, 0, 0, 0);
    ak = __builtin_amdgcn_mfma_f32_32x32x16_bf16(ldA(krw), bfr, ak, 0, 0, 0);
    av = __builtin_amdgcn_mfma_f32_32x32x16_bf16(ldA(vrw), bfr, av, 0, 0, 0);
  }

  #pragma unroll
  for (int cg = 0; cg < 4; ++cg) {
    int h = 4*m + cg, d0 = 4*g;
    size_t rb = ((size_t)(b*NH_ + h)*N_ + nglob)*16 + d0;
    uint2 wqv;
    wqv.x = pkbf(aq[cg*4+0]*QS, aq[cg*4+1]*QS);
    wqv.y = pkbf(aq[cg*4+2]*QS, aq[cg*4+3]*QS);
    *reinterpret_cast<uint2*>(qt + rb) = wqv;
    uint2 wkv;
    wkv.x = pkbf(ak[cg*4+0], ak[cg*4+1]);
    wkv.y = pkbf(ak[cg*4+2], ak[cg*4+3]);
    *reinterpret_cast<uint2*>(kt + rb) = wkv;
    unsigned r0 = pkbf(av[cg*4+0], av[cg*4+1]);
    unsigned r1 = pkbf(av[cg*4+2], av[cg*4+3]);
    size_t vb0 = ((size_t)(b*NH_+h)*16 + d0)*N_ + nglob;
    vt[vb0]                = (unsigned short)r0;
    vt[vb0 + N_]           = (unsigned short)(r0 >> 16);
    vt[vb0 + 2*(size_t)N_] = (unsigned short)r1;
    vt[vb0 + 3*(size_t)N_] = (unsigned short)(r1 >> 16);
  }
}

// K7: MFMA flash attention v8: ONE WAVE PER BLOCK (no LDS, no barriers), global
// atomic combine into part_g (zeroed by k_pool). grid = 16bh x 49qt x 2half x 4kh.
__global__ __launch_bounds__(64, 4) void k_attn8(const unsigned short* __restrict__ qt,
    const unsigned short* __restrict__ kt, const unsigned short* __restrict__ vt,
    const unsigned short* __restrict__ vz, float* __restrict__ part_g) {
  int lane = threadIdx.x;
  int l31 = lane & 31, g = lane >> 5;
  int bh = blockIdx.x & 15;
  int rest = blockIdx.x >> 4;          // 0..391
  int kh = rest & 3;
  int half = (rest >> 2) & 1;
  int qti = rest >> 3;                 // 0..48
  int qbase = qti * 64;

  bf16x8 qfA = __builtin_bit_cast(bf16x8,
      *reinterpret_cast<const uint4*>(qt + ((size_t)bh*N_ + qbase + l31)*16 + g*8));
  bf16x8 qfB = __builtin_bit_cast(bf16x8,
      *reinterpret_cast<const uint4*>(qt + ((size_t)bh*N_ + qbase + 32 + l31)*16 + g*8));
  f32x16 zf, accA, accB;
  #pragma unroll
  for (int i = 0; i < 16; ++i) { zf[i] = 0.f; accA[i] = 0.f; accB[i] = 0.f; }
  const unsigned short* krow = kt + (size_t)bh*N_*16 + g*8;
  const unsigned short* vbase = (l31 < 16) ? (vt + ((size_t)bh*16 + l31)*(size_t)N_) : vz;

  auto ld = [&](const unsigned short* p) {
    return __builtin_bit_cast(bf16x8, *reinterpret_cast<const uint4*>(p));
  };
  auto halfstep = [&](const f32x16& sa, f32x16& acc, bf16x8 v1, bf16x8 v2) {
    float p[16];
    #pragma unroll
    for (int r = 0; r < 16; ++r) p[r] = fast_exp2(sa[r]);
    unsigned u01 = pkbf(p[0],p[1]),  u23 = pkbf(p[2],p[3]);
    unsigned u45 = pkbf(p[4],p[5]),  u67 = pkbf(p[6],p[7]);
    unsigned u89 = pkbf(p[8],p[9]),  uab = pkbf(p[10],p[11]);
    unsigned ucd = pkbf(p[12],p[13]), uef = pkbf(p[14],p[15]);
    plane32_swap(u01, u45);
    plane32_swap(u23, u67);
    plane32_swap(u89, ucd);
    plane32_swap(uab, uef);
    bf16x8 pf1 = __builtin_bit_cast(bf16x8, make_uint4(u01, u23, u45, u67));
    bf16x8 pf2 = __builtin_bit_cast(bf16x8, make_uint4(u89, uab, ucd, uef));
    acc = __builtin_amdgcn_mfma_f32_32x32x16_bf16(v1, pf1, acc, 0, 0, 0);
    acc = __builtin_amdgcn_mfma_f32_32x32x16_bf16(v2, pf2, acc, 0, 0, 0);
  };

  int tb0 = (half*49 + kh*12) * 32;
  const unsigned short* kp  = krow  + (size_t)(tb0 + l31)*16;
  const unsigned short* vp1 = vbase + tb0 + g*8;
  const unsigned short* vp2 = vp1 + 16;

  bf16x8 kfN = ld(kp), v1N = ld(vp1), v2N = ld(vp2);
  #pragma unroll 4
  for (int j = 0; j < 12; ++j) {
    bf16x8 kf = kfN, v1 = v1N, v2 = v2N;
    if (j < 11) {
      kfN = ld(kp  + (size_t)(j+1)*512);
      v1N = ld(vp1 + (j+1)*32);
      v2N = ld(vp2 + (j+1)*32);
    }
    f32x16 sA = __builtin_amdgcn_mfma_f32_32x32x16_bf16(kf, qfA, zf, 0, 0, 0);
    f32x16 sB = __builtin_amdgcn_mfma_f32_32x32x16_bf16(kf, qfB, zf, 0, 0, 0);
    halfstep(sA, accA, v1, v2);
    halfstep(sB, accB, v1, v2);
  }
  if (kh == 0) {
    int tb = (half*49 + 48) * 32;
    bf16x8 kf = ld(krow + (size_t)(tb + l31)*16);
    bf16x8 v1 = ld(vbase + tb + g*8);
    bf16x8 v2 = ld(vbase + tb + 16 + g*8);
    f32x16 sA = __builtin_amdgcn_mfma_f32_32x32x16_bf16(kf, qfA, zf, 0, 0, 0);
    f32x16 sB = __builtin_amdgcn_mfma_f32_32x32x16_bf16(kf, qfB, zf, 0, 0, 0);
    halfstep(sA, accA, v1, v2);
    halfstep(sB, accB, v1, v2);
  }

  float* pg = part_g + ((((size_t)half*16 + bh)*2 + g)*5)*N_ + qbase + l31;
  #pragma unroll
  for (int j = 0; j < 5; ++j) {
    atomicAdd(&pg[(size_t)j*N_],      accA[j]);
    atomicAdd(&pg[(size_t)j*N_ + 32], accB[j]);
  }
}

// K8: proj_out MFMA GEMM reading attention partials directly; outc stored bf16;
// GroupNorm partial sums (atomicAdd into gst, zeroed by k_fused).
__global__ __launch_bounds__(128) void k_proj3(const float* __restrict__ part_g,
    const float* __restrict__ pw, unsigned short* __restrict__ outc, float* __restrict__ gst) {
  int bid = blockIdx.x;
  int nb = bid % 49, ct = (bid / 49) % 8, b = bid / (49*8);
  int wave = threadIdx.x >> 6, lane = threadIdx.x & 63;
  int l31 = lane & 31, g = lane >> 5;
  int n0 = nb*64, c0 = ct*32;
  int nw = n0 + wave*32;

  __shared__ float invs[8][64];
  for (int u = threadIdx.x; u < 512; u += 128) {
    int h = u >> 6, n = u & 63;
    size_t r0 = ((((size_t)0*16 + b*8 + h)*2 + 0)*5 + 4)*N_ + n0 + n;
    size_t r1 = ((((size_t)1*16 + b*8 + h)*2 + 0)*5 + 4)*N_ + n0 + n;
    invs[h][n] = 1.f / (part_g[r0] + part_g[r1]);
  }
  __syncthreads();

  const float* wrow = pw + (size_t)(c0 + l31)*IN_;
  bf16x8 afr[4];
  #pragma unroll
  for (int kk = 0; kk < 4; ++kk) {
    const float4* fp = reinterpret_cast<const float4*>(wrow + kk*16 + g*8);
    float4 f0 = fp[0], f1 = fp[1];
    uint4 u;
    u.x = pkbf(f0.x, f0.y); u.y = pkbf(f0.z, f0.w);
    u.z = pkbf(f1.x, f1.y); u.w = pkbf(f1.z, f1.w);
    afr[kk] = __builtin_bit_cast(bf16x8, u);
  }

  f32x16 acc;
  #pragma unroll
  for (int i = 0; i < 16; ++i) acc[i] = 0.f;
  #pragma unroll
  for (int kk = 0; kk < 4; ++kk) {
    int h = kk*2 + g;
    float iv = invs[h][wave*32 + l31];
    const float* p0 = part_g + (((size_t)0*16 + b*8 + h)*2)*5*N_ + nw + l31;
    const float* p1 = part_g + (((size_t)1*16 + b*8 + h)*2)*5*N_ + nw + l31;
    unsigned words[4];
    #pragma unroll
    for (int ep = 0; ep < 4; ++ep) {
      float vv[2];
      #pragma unroll
      for (int e2 = 0; e2 < 2; ++e2) {
        int d = ep*2 + e2;
        int gr = d >> 2, j = d & 3;
        size_t off = ((size_t)gr*5 + j)*N_;
        vv[e2] = (p0[off] + p1[off]) * iv;
      }
      words[ep] = pkbf(vv[0], vv[1]);
    }
    uint4 bu = make_uint4(words[0], words[1], words[2], words[3]);
    acc = __builtin_amdgcn_mfma_f32_32x32x16_bf16(afr[kk], __builtin_bit_cast(bf16x8, bu), acc, 0, 0, 0);
  }

  unsigned short* op = outc + ((size_t)b*C_ + c0)*N_ + nw + l31;
  #pragma unroll
  for (int reg = 0; reg < 16; ++reg) {
    int row = (reg & 3) + 8*(reg >> 2) + 4*g;
    __bf16 vb = (__bf16)acc[reg];
    op[(size_t)row*N_] = __builtin_bit_cast(unsigned short, vb);
  }

  // GN partials from fp32 accumulators
  float s4[4], q4[4];
  #pragma unroll
  for (int gl = 0; gl < 4; ++gl) {
    s4[gl] = acc[gl*4+0] + acc[gl*4+1] + acc[gl*4+2] + acc[gl*4+3];
    q4[gl] = acc[gl*4+0]*acc[gl*4+0] + acc[gl*4+1]*acc[gl*4+1]
           + acc[gl*4+2]*acc[gl*4+2] + acc[gl*4+3]*acc[gl*4+3];
  }
  #pragma unroll
  for (int gl = 0; gl < 4; ++gl) {
    #pragma unroll
    for (int off = 32; off > 0; off >>= 1) {
      s4[gl] += __shfl_xor(s4[gl], off);
      q4[gl] += __shfl_xor(q4[gl], off);
    }
  }
  __shared__ float red[2][4][2];
  if (lane == 0) {
    #pragma unroll
    for (int gl = 0; gl < 4; ++gl) { red[wave][gl][0] = s4[gl]; red[wave][gl][1] = q4[gl]; }
  }
  __syncthreads();
  if (threadIdx.x < 8) {
    int gl = threadIdx.x >> 1, which = threadIdx.x & 1;
    float v = red[0][gl][which] + red[1][gl][which];
    atomicAdd(&gst[((size_t)b*32 + ct*4 + gl)*2 + which], v);
  }
}

// K10: out = x + GN(outc_bf16)*gamma + beta, 8 elements/thread.
__global__ __launch_bounds__(256) void k_final(const float* __restrict__ x,
    const unsigned short* __restrict__ outc, const float* __restrict__ gst,
    const float* __restrict__ gng, const float* __restrict__ gnb, float* __restrict__ out) {
  int tid = blockIdx.x*256 + threadIdx.x;
  size_t idx = (size_t)tid * 8;
  int c = (int)((idx / N_) % C_);
  int b = (int)(idx / ((size_t)C_*N_));
  int g = c >> 3;
  float S  = gst[(b*32+g)*2];
  float SS = gst[(b*32+g)*2+1];
  const float invn = 1.f/(8.f*N_);
  float mu = S * invn;
  float var = SS * invn - mu*mu;
  float rs = rsqrtf(var + EPSF);
  float ga = gng[c], be = gnb[c];
  float4 xv0 = *reinterpret_cast<const float4*>(x + idx);
  float4 xv1 = *reinterpret_cast<const float4*>(x + idx + 4);
  uint4 ou = *reinterpret_cast<const uint4*>(outc + idx);
  float o[8];
  o[0] = bf2f((unsigned short)(ou.x & 0xffff)); o[1] = bf2f((unsigned short)(ou.x >> 16));
  o[2] = bf2f((unsigned short)(ou.y & 0xffff)); o[3] = bf2f((unsigned short)(ou.y >> 16));
  o[4] = bf2f((unsigned short)(ou.z & 0xffff)); o[5] = bf2f((unsigned short)(ou.z >> 16));
  o[6] = bf2f((unsigned short)(ou.w & 0xffff)); o[7] = bf2f((unsigned short)(ou.w >> 16));
  float4 r0, r1;
  r0.x = xv0.x + (o[0] - mu)*rs*ga + be;
  r0.y = xv0.y + (o[1] - mu)*rs*ga + be;
  r0.z = xv0.z + (o[2] - mu)*rs*ga + be;
  r0.w = xv0.w + (o[3] - mu)*rs*ga + be;
  r1.x = xv1.x + (o[4] - mu)*rs*ga + be;
  r1.y = xv1.y + (o[5] - mu)*rs*ga + be;
  r1.z = xv1.z + (o[6] - mu)*rs*ga + be;
  r1.w = xv1.w + (o[7] - mu)*rs*ga + be;
  *reinterpret_cast<float4*>(out + idx)     = r0;
  *reinterpret_cast<float4*>(out + idx + 4) = r1;
}

extern "C" void kernel_launch(void* const* d_in, const int* in_sizes, int n_in,
                              void* d_out, int out_size, void* d_ws, size_t ws_size,
                              hipStream_t stream) {
  const float* x   = (const float*)d_in[0];
  const float* gcw = (const float*)d_in[1];
  const float* bng = (const float*)d_in[2];
  const float* bnb = (const float*)d_in[3];
  const float* bnm = (const float*)d_in[4];
  const float* bnv = (const float*)d_in[5];
  const float* ghw = (const float*)d_in[6];
  const float* gww = (const float*)d_in[7];
  const float* piw = (const float*)d_in[8];
  const float* lng = (const float*)d_in[9];
  const float* lnb = (const float*)d_in[10];
  const float* wq  = (const float*)d_in[11];
  const float* wk  = (const float*)d_in[12];
  const float* wv  = (const float*)d_in[13];
  const float* pw  = (const float*)d_in[14];
  const float* gng = (const float*)d_in[15];
  const float* gnb = (const float*)d_in[16];
  float* ws  = (float*)d_ws;
  float* out = (float*)d_out;
  unsigned short* qt   = (unsigned short*)(ws + O_QT);
  unsigned short* kt   = (unsigned short*)(ws + O_KT);
  unsigned short* vt   = (unsigned short*)(ws + O_VT);
  unsigned short* vz   = (unsigned short*)(ws + O_VZ);
  unsigned short* outc = (unsigned short*)(ws + O_OUTC);

  k_pool<<<B_*C_, 256, 0, stream>>>(x, ws + O_POOL, ws + O_PART);
  k_gates2<<<B_*H_, 256, 0, stream>>>(gcw, ws+O_POOL, bng, bnb, bnm, bnv, ghw, gww, ws+O_GH, ws+O_GW);
  k_fused<<<B_*49, 256, 0, stream>>>(x, piw, lng, lnb, wq, wk, wv, ws+O_GH, ws+O_GW,
                                     qt, kt, vt, vz, ws+O_GST);
  k_attn8<<<16*392, 64, 0, stream>>>(qt, kt, vt, vz, ws+O_PART);
  k_proj3<<<B_*8*49, 128, 0, stream>>>(ws+O_PART, pw, outc, ws+O_GST);
  k_final<<<(B_*C_*N_)/(8*256), 256, 0, stream>>>(x, outc, ws+O_GST, gng, gnb, out);
}

// Round 14
// 80.308 us; speedup vs baseline: 1.0270x; 1.0270x over previous
//
#include <hip/hip_runtime.h>
#include <math.h>

#define EPSF 1e-5f

constexpr int B_ = 2, C_ = 256, H_ = 56, W_ = 56, N_ = 3136;
constexpr int MID_ = 32, L_ = 112, IN_ = 64, NH_ = 8;

typedef __attribute__((ext_vector_type(8))) __bf16 bf16x8;
typedef __attribute__((ext_vector_type(16))) float f32x16;

// workspace offsets (in floats; all multiples of 4 for 16B alignment)
constexpr size_t O_POOL = 0;
constexpr size_t O_GH   = O_POOL + (size_t)B_*C_*L_;             // ghT [b][H][C]
constexpr size_t O_GW   = O_GH   + (size_t)B_*C_*H_;             // gwT [b][W][C]
constexpr size_t O_QT   = O_GW   + (size_t)B_*C_*W_;             // bf16 [16bh][N][16]
constexpr size_t O_KT   = O_QT   + (size_t)B_*NH_*N_*16/2;
constexpr size_t O_VT   = O_KT   + (size_t)B_*NH_*N_*16/2;       // bf16 [16bh][16][N]
constexpr size_t O_VZ   = O_VT   + (size_t)B_*NH_*16*N_/2;       // bf16 zero row [N]
constexpr size_t O_OUTC = O_VZ   + N_/2;                          // bf16 [B][C][N]
constexpr size_t O_GST  = O_OUTC + (size_t)B_*C_*N_/2;           // fp32 [b*32+g][2] = {S, SS}
constexpr size_t O_PART = O_GST  + (size_t)B_*32*2;              // fp32 [2half][16bh][2g][5][N]

__device__ inline unsigned pkbf(float lo, float hi) {
  __bf16 a = (__bf16)lo, c = (__bf16)hi;
  return (unsigned)__builtin_bit_cast(unsigned short, a)
       | ((unsigned)__builtin_bit_cast(unsigned short, c) << 16);
}

__device__ inline float bf2f(unsigned short u) {
  unsigned v = (unsigned)u << 16;
  return __builtin_bit_cast(float, v);
}

__device__ inline float fast_exp2(float x) {
#if __has_builtin(__builtin_amdgcn_exp2f)
  return __builtin_amdgcn_exp2f(x);
#else
  float r; asm("v_exp_f32 %0, %1" : "=v"(r) : "v"(x)); return r;
#endif
}

__device__ inline void plane32_swap(unsigned &a, unsigned &b) {
#if __has_builtin(__builtin_amdgcn_permlane32_swap)
  typedef unsigned uv2 __attribute__((ext_vector_type(2)));
  uv2 r = __builtin_amdgcn_permlane32_swap(a, b, false, false);
  a = r.x; b = r.y;
#else
  asm volatile("v_permlane32_swap_b32 %0, %1" : "+v"(a), "+v"(b));
#endif
}

// K1: h_pool / w_pool. one block per (b,c). float4 staging, 224-thread reduce.
__global__ __launch_bounds__(256) void k_pool(const float* __restrict__ x, float* __restrict__ pool) {
  int bc = blockIdx.x;
  const float4* xp4 = reinterpret_cast<const float4*>(x + (size_t)bc * N_);
  __shared__ float tile[N_];
  float4* t4 = reinterpret_cast<float4*>(tile);
  for (int i = threadIdx.x; i < N_/4; i += 256) t4[i] = xp4[i];
  __syncthreads();
  int t = threadIdx.x;
  if (t < 224) {
    int o = t >> 1, half = t & 1;
    float r = 0.f;
    if (o < 56) {
      const float* row = tile + o*W_ + half*28;
      #pragma unroll 7
      for (int j = 0; j < 28; ++j) r += row[j];
    } else {
      const float* col = tile + (half*28)*W_ + (o - 56);
      #pragma unroll 7
      for (int j = 0; j < 28; ++j) r += col[j*W_];
    }
    r += __shfl_xor(r, 1);
    if (half == 0) pool[(size_t)bc*L_ + o] = r * (1.f/56.f);
  }
}

// K3': gates with inline cat recompute. grid = B*H = 112 blocks.
__global__ __launch_bounds__(256) void k_gates2(const float* __restrict__ gcw, const float* __restrict__ pool,
    const float* __restrict__ bng, const float* __restrict__ bnb,
    const float* __restrict__ bnm, const float* __restrict__ bnv,
    const float* __restrict__ ghw, const float* __restrict__ gww,
    float* __restrict__ ghT, float* __restrict__ gwT) {
  int b = blockIdx.x / H_;
  int p = blockIdx.x % H_;
  __shared__ float cat_s[2][MID_];
  int t = threadIdx.x;
  {
    int out = t >> 2, sub = t & 3;
    int m = out & 31, which = out >> 5;
    int l = p + which*H_;
    const float* pp = pool + (size_t)b*C_*L_ + l;
    const float* wp = gcw + (size_t)m*C_ + sub*64;
    float s = 0.f;
    #pragma unroll 16
    for (int c = 0; c < 64; ++c) s += wp[c] * pp[(size_t)(sub*64 + c)*L_];
    s += __shfl_xor(s, 1); s += __shfl_xor(s, 2);
    if (sub == 0) {
      float xn = (s - bnm[m]) * rsqrtf(bnv[m] + EPSF) * bng[m] + bnb[m];
      cat_s[which][m] = xn * fminf(fmaxf(xn + 3.f, 0.f), 6.f) * (1.f/6.f);
    }
  }
  __syncthreads();
  int c = t;
  float sh = 0.f, sw = 0.f;
  #pragma unroll 8
  for (int m = 0; m < MID_; ++m) {
    sh += ghw[c*MID_ + m] * cat_s[0][m];
    sw += gww[c*MID_ + m] * cat_s[1][m];
  }
  ghT[((size_t)b*H_ + p)*C_ + c] = 1.f/(1.f + expf(-sh));
  gwT[((size_t)b*W_ + p)*C_ + c] = 1.f/(1.f + expf(-sw));
}

// K5: fused bias + proj_in GEMM (MFMA) + LayerNorm + QKV GEMM (MFMA) + layout packing.
// Also zeroes gst (block 0).
__global__ __launch_bounds__(256) void k_fused(const float* __restrict__ x,
    const float* __restrict__ piw, const float* __restrict__ lng, const float* __restrict__ lnb,
    const float* __restrict__ wq, const float* __restrict__ wk, const float* __restrict__ wv,
    const float* __restrict__ ghT, const float* __restrict__ gwT,
    unsigned short* __restrict__ qt, unsigned short* __restrict__ kt,
    unsigned short* __restrict__ vt, unsigned short* __restrict__ vz,
    float* __restrict__ gst) {
  __shared__ __align__(16) unsigned short sT[64][72];
  __shared__ float ps[2][2][64][2];
  __shared__ float lg[64], lb[64];
  __shared__ float bias_s[64];
  int b = blockIdx.x / 49, n0 = (blockIdx.x % 49) * 64;
  int tid = threadIdx.x;
  int wv_ = tid >> 6, lane = tid & 63;
  int m = wv_ & 1, nh = wv_ >> 1, l31 = lane & 31, g = lane >> 5;
  int nloc = nh*32 + l31;
  int nglob = n0 + nloc;
  const float QS = 0.35355339059327373f * 1.4426950408889634f;  // scale * log2(e)

  if (tid < 64) { lg[tid] = lng[tid]; lb[tid] = lnb[tid]; }
  if (blockIdx.x == 0 && tid < B_*32*2) gst[tid] = 0.f;

  {
    int px = tid >> 2, sub = tid & 3;
    int n = n0 + px;
    int h = n / W_, w = n % W_;
    const float4* gh4 = reinterpret_cast<const float4*>(ghT + ((size_t)b*H_ + h)*C_ + sub*64);
    const float4* gw4 = reinterpret_cast<const float4*>(gwT + ((size_t)b*W_ + w)*C_ + sub*64);
    float s = 0.f;
    #pragma unroll
    for (int i = 0; i < 16; ++i) {
      float4 a = gh4[i], c2 = gw4[i];
      s += a.x*c2.x + a.y*c2.y + a.z*c2.z + a.w*c2.w;
    }
    s += __shfl_xor(s, 1); s += __shfl_xor(s, 2);
    if (sub == 0)
      bias_s[px] = fmaxf(logf(s * (1.f/C_)), -5.f) * 1.4426950408889634f;
  }
  __syncthreads();

  for (int u = tid; u < 512; u += 256) {
    int h = u >> 6, n = u & 63;
    size_t base = ((size_t)(b*NH_ + h)*N_ + n0 + n)*16;
    *reinterpret_cast<uint4*>(qt + base + 8) = make_uint4(0x3F803F80u, 0u, 0u, 0u);
    float bv = bias_s[n];
    __bf16 bhi = (__bf16)bv; float blo = bv - (float)bhi;
    *reinterpret_cast<uint4*>(kt + base + 8) = make_uint4(pkbf((float)bhi, blo), 0u, 0u, 0u);
  }
  for (int u = tid; u < 512; u += 256) {
    int rr = u >> 3, chunk = u & 7;
    int h = rr >> 3, r = 8 + (rr & 7);
    unsigned val = (r == 8 || r == 12) ? 0x3F803F80u : 0u;
    *reinterpret_cast<uint4*>(vt + ((size_t)(b*NH_+h)*16 + r)*N_ + n0 + chunk*8)
        = make_uint4(val, val, val, val);
  }
  if (b == 0 && tid < 8)
    *reinterpret_cast<uint4*>(vz + n0 + tid*8) = make_uint4(0u, 0u, 0u, 0u);

  // GEMM1: seq_pre[i][n] = sum_c piw[i][c] * x[b][c][n]
  const float* arow = piw + (size_t)(32*m + l31)*C_;
  const float* xcol = x + (size_t)b*C_*N_ + nglob;
  f32x16 acc;
  #pragma unroll
  for (int i = 0; i < 16; ++i) acc[i] = 0.f;
  #pragma unroll 4
  for (int kk = 0; kk < 16; ++kk) {
    const float4* ap = reinterpret_cast<const float4*>(arow + kk*16 + g*8);
    float4 a0 = ap[0], a1 = ap[1];
    uint4 au;
    au.x = pkbf(a0.x, a0.y); au.y = pkbf(a0.z, a0.w);
    au.z = pkbf(a1.x, a1.y); au.w = pkbf(a1.z, a1.w);
    float bvl[8];
    #pragma unroll
    for (int e = 0; e < 8; ++e) bvl[e] = xcol[(size_t)(kk*16 + g*8 + e)*N_];
    uint4 bu;
    bu.x = pkbf(bvl[0], bvl[1]); bu.y = pkbf(bvl[2], bvl[3]);
    bu.z = pkbf(bvl[4], bvl[5]); bu.w = pkbf(bvl[6], bvl[7]);
    acc = __builtin_amdgcn_mfma_f32_32x32x16_bf16(
        __builtin_bit_cast(bf16x8, au), __builtin_bit_cast(bf16x8, bu), acc, 0, 0, 0);
  }

  float s = 0.f, ss = 0.f;
  #pragma unroll
  for (int i = 0; i < 16; ++i) { s += acc[i]; ss += acc[i]*acc[i]; }
  ps[m][g][nloc][0] = s; ps[m][g][nloc][1] = ss;
  __syncthreads();
  float S  = ps[0][0][nloc][0] + ps[0][1][nloc][0] + ps[1][0][nloc][0] + ps[1][1][nloc][0];
  float SS = ps[0][0][nloc][1] + ps[0][1][nloc][1] + ps[1][0][nloc][1] + ps[1][1][nloc][1];
  float mu = S * (1.f/IN_);
  float var = SS * (1.f/IN_) - mu*mu;
  float rsd = rsqrtf(var + EPSF);

  #pragma unroll
  for (int cg = 0; cg < 4; ++cg) {
    int jb = 8*cg + 4*g + 32*m;
    float v0 = (acc[cg*4+0]-mu)*rsd*lg[jb+0] + lb[jb+0];
    float v1 = (acc[cg*4+1]-mu)*rsd*lg[jb+1] + lb[jb+1];
    float v2 = (acc[cg*4+2]-mu)*rsd*lg[jb+2] + lb[jb+2];
    float v3 = (acc[cg*4+3]-mu)*rsd*lg[jb+3] + lb[jb+3];
    uint2 w; w.x = pkbf(v0, v1); w.y = pkbf(v2, v3);
    *reinterpret_cast<uint2*>(&sT[nloc][jb]) = w;
  }
  __syncthreads();

  // GEMM2: q/k/v[i][n] = sum_j w[i][j] * seq[n][j]
  f32x16 aq, ak, av;
  #pragma unroll
  for (int i = 0; i < 16; ++i) { aq[i] = 0.f; ak[i] = 0.f; av[i] = 0.f; }
  const float* qrw = wq + (size_t)(32*m + l31)*IN_;
  const float* krw = wk + (size_t)(32*m + l31)*IN_;
  const float* vrw = wv + (size_t)(32*m + l31)*IN_;
  #pragma unroll
  for (int kk = 0; kk < 4; ++kk) {
    bf16x8 bfr = __builtin_bit_cast(bf16x8,
        *reinterpret_cast<const uint4*>(&sT[nloc][kk*16 + g*8]));
    auto ldA = [&](const float* wrow) {
      const float4* fp = reinterpret_cast<const float4*>(wrow + kk*16 + g*8);
      float4 f0 = fp[0], f1 = fp[1];
      uint4 u;
      u.x = pkbf(f0.x, f0.y); u.y = pkbf(f0.z, f0.w);
      u.z = pkbf(f1.x, f1.y); u.w = pkbf(f1.z, f1.w);
      return __builtin_bit_cast(bf16x8, u);
    };
    aq = __builtin_amdgcn_mfma_f32_32x32x16_bf16(ldA(qrw), bfr, aq, 0, 0, 0);
    ak = __builtin_amdgcn_mfma_f32_32x32x16_bf16(ldA(krw), bfr, ak, 0, 0, 0);
    av = __builtin_amdgcn_mfma_f32_32x32x16_bf16(ldA(vrw), bfr, av, 0, 0, 0);
  }

  #pragma unroll
  for (int cg = 0; cg < 4; ++cg) {
    int h = 4*m + cg, d0 = 4*g;
    size_t rb = ((size_t)(b*NH_ + h)*N_ + nglob)*16 + d0;
    uint2 wqv;
    wqv.x = pkbf(aq[cg*4+0]*QS, aq[cg*4+1]*QS);
    wqv.y = pkbf(aq[cg*4+2]*QS, aq[cg*4+3]*QS);
    *reinterpret_cast<uint2*>(qt + rb) = wqv;
    uint2 wkv;
    wkv.x = pkbf(ak[cg*4+0], ak[cg*4+1]);
    wkv.y = pkbf(ak[cg*4+2], ak[cg*4+3]);
    *reinterpret_cast<uint2*>(kt + rb) = wkv;
    unsigned r0 = pkbf(av[cg*4+0], av[cg*4+1]);
    unsigned r1 = pkbf(av[cg*4+2], av[cg*4+3]);
    size_t vb0 = ((size_t)(b*NH_+h)*16 + d0)*N_ + nglob;
    vt[vb0]                = (unsigned short)r0;
    vt[vb0 + N_]           = (unsigned short)(r0 >> 16);
    vt[vb0 + 2*(size_t)N_] = (unsigned short)r1;
    vt[vb0 + 3*(size_t)N_] = (unsigned short)(r1 >> 16);
  }
}

// K7: MFMA flash attention v9: 2-stage score pipeline.
// iter j: load tile j+2; s(j+1)=MFMA(kf(j+1)) [loaded last iter]; halfstep(s(j)) [computed last iter].
// grid = 16 bh x (49 qtiles x 2 key-halves); 4 waves = 4 key chunks; LDS partial combine.
__global__ __launch_bounds__(256, 3) void k_attn9(const unsigned short* __restrict__ qt,
    const unsigned short* __restrict__ kt, const unsigned short* __restrict__ vt,
    const unsigned short* __restrict__ vz, float* __restrict__ part_g) {
  int tid = threadIdx.x;
  int lane = tid & 63, kh = tid >> 6;
  int l31 = lane & 31, g = lane >> 5;
  int bh = blockIdx.x & 15;
  int rest = blockIdx.x >> 4;          // 0..97
  int qti = rest >> 1, half = rest & 1;
  int qbase = qti * 64;

  bf16x8 qfA = __builtin_bit_cast(bf16x8,
      *reinterpret_cast<const uint4*>(qt + ((size_t)bh*N_ + qbase + l31)*16 + g*8));
  bf16x8 qfB = __builtin_bit_cast(bf16x8,
      *reinterpret_cast<const uint4*>(qt + ((size_t)bh*N_ + qbase + 32 + l31)*16 + g*8));
  f32x16 zf, accA, accB;
  #pragma unroll
  for (int i = 0; i < 16; ++i) { zf[i] = 0.f; accA[i] = 0.f; accB[i] = 0.f; }
  const unsigned short* krow = kt + (size_t)bh*N_*16 + g*8;
  const unsigned short* vbase = (l31 < 16) ? (vt + ((size_t)bh*16 + l31)*(size_t)N_) : vz;

  auto ld = [&](const unsigned short* p) {
    return __builtin_bit_cast(bf16x8, *reinterpret_cast<const uint4*>(p));
  };
  auto halfstep = [&](const f32x16& sa, f32x16& acc, bf16x8 v1, bf16x8 v2) {
    float p[16];
    #pragma unroll
    for (int r = 0; r < 16; ++r) p[r] = fast_exp2(sa[r]);
    unsigned u01 = pkbf(p[0],p[1]),  u23 = pkbf(p[2],p[3]);
    unsigned u45 = pkbf(p[4],p[5]),  u67 = pkbf(p[6],p[7]);
    unsigned u89 = pkbf(p[8],p[9]),  uab = pkbf(p[10],p[11]);
    unsigned ucd = pkbf(p[12],p[13]), uef = pkbf(p[14],p[15]);
    plane32_swap(u01, u45);
    plane32_swap(u23, u67);
    plane32_swap(u89, ucd);
    plane32_swap(uab, uef);
    bf16x8 pf1 = __builtin_bit_cast(bf16x8, make_uint4(u01, u23, u45, u67));
    bf16x8 pf2 = __builtin_bit_cast(bf16x8, make_uint4(u89, uab, ucd, uef));
    acc = __builtin_amdgcn_mfma_f32_32x32x16_bf16(v1, pf1, acc, 0, 0, 0);
    acc = __builtin_amdgcn_mfma_f32_32x32x16_bf16(v2, pf2, acc, 0, 0, 0);
  };

  int tb0 = (half*49 + kh*12) * 32;
  const unsigned short* kp  = krow  + (size_t)(tb0 + l31)*16;   // +512 ushorts/tile
  const unsigned short* vp1 = vbase + tb0 + g*8;                // +32 ushorts/tile
  const unsigned short* vp2 = vp1 + 16;

  // prologue: tiles 0,1
  bf16x8 kf0  = ld(kp);
  bf16x8 v1_0 = ld(vp1),      v2_0 = ld(vp2);
  bf16x8 kf1  = ld(kp + 512);
  bf16x8 v1_1 = ld(vp1 + 32), v2_1 = ld(vp2 + 32);
  f32x16 sA0 = __builtin_amdgcn_mfma_f32_32x32x16_bf16(kf0, qfA, zf, 0, 0, 0);
  f32x16 sB0 = __builtin_amdgcn_mfma_f32_32x32x16_bf16(kf0, qfB, zf, 0, 0, 0);

  #pragma unroll 2
  for (int j = 0; j < 10; ++j) {
    bf16x8 kfn = ld(kp  + (size_t)(j+2)*512);
    bf16x8 v1n = ld(vp1 + (j+2)*32);
    bf16x8 v2n = ld(vp2 + (j+2)*32);
    f32x16 sA1 = __builtin_amdgcn_mfma_f32_32x32x16_bf16(kf1, qfA, zf, 0, 0, 0);
    f32x16 sB1 = __builtin_amdgcn_mfma_f32_32x32x16_bf16(kf1, qfB, zf, 0, 0, 0);
    halfstep(sA0, accA, v1_0, v2_0);
    halfstep(sB0, accB, v1_0, v2_0);
    sA0 = sA1; sB0 = sB1;
    kf1 = kfn;
    v1_0 = v1_1; v2_0 = v2_1; v1_1 = v1n; v2_1 = v2n;
  }
  {
    f32x16 sA1 = __builtin_amdgcn_mfma_f32_32x32x16_bf16(kf1, qfA, zf, 0, 0, 0);
    f32x16 sB1 = __builtin_amdgcn_mfma_f32_32x32x16_bf16(kf1, qfB, zf, 0, 0, 0);
    halfstep(sA0, accA, v1_0, v2_0);
    halfstep(sB0, accB, v1_0, v2_0);
    halfstep(sA1, accA, v1_1, v2_1);
    halfstep(sB1, accB, v1_1, v2_1);
  }
  if (kh == 0) {
    int tb = (half*49 + 48) * 32;
    bf16x8 kf = ld(krow + (size_t)(tb + l31)*16);
    bf16x8 v1 = ld(vbase + tb + g*8);
    bf16x8 v2 = ld(vbase + tb + 16 + g*8);
    f32x16 sA = __builtin_amdgcn_mfma_f32_32x32x16_bf16(kf, qfA, zf, 0, 0, 0);
    f32x16 sB = __builtin_amdgcn_mfma_f32_32x32x16_bf16(kf, qfB, zf, 0, 0, 0);
    halfstep(sA, accA, v1, v2);
    halfstep(sB, accB, v1, v2);
  }

  __shared__ float part[3][2][64][5];
  if (kh > 0) {
    #pragma unroll
    for (int j = 0; j < 5; ++j) {
      part[kh-1][0][lane][j] = accA[j];
      part[kh-1][1][lane][j] = accB[j];
    }
  }
  __syncthreads();
  if (kh == 0) {
    float rA[5], rB[5];
    #pragma unroll
    for (int j = 0; j < 5; ++j) { rA[j] = accA[j]; rB[j] = accB[j]; }
    #pragma unroll
    for (int c = 0; c < 3; ++c) {
      #pragma unroll
      for (int j = 0; j < 5; ++j) {
        rA[j] += part[c][0][lane][j];
        rB[j] += part[c][1][lane][j];
      }
    }
    float* pg = part_g + ((((size_t)half*16 + bh)*2 + g)*5)*N_ + qbase + l31;
    #pragma unroll
    for (int j = 0; j < 5; ++j) {
      pg[(size_t)j*N_]      = rA[j];
      pg[(size_t)j*N_ + 32] = rB[j];
    }
  }
}

// K8: proj_out MFMA GEMM reading attention partials directly; outc stored bf16;
// GroupNorm partial sums (atomicAdd into gst, zeroed by k_fused).
__global__ __launch_bounds__(128) void k_proj3(const float* __restrict__ part_g,
    const float* __restrict__ pw, unsigned short* __restrict__ outc, float* __restrict__ gst) {
  int bid = blockIdx.x;
  int nb = bid % 49, ct = (bid / 49) % 8, b = bid / (49*8);
  int wave = threadIdx.x >> 6, lane = threadIdx.x & 63;
  int l31 = lane & 31, g = lane >> 5;
  int n0 = nb*64, c0 = ct*32;
  int nw = n0 + wave*32;

  __shared__ float invs[8][64];
  for (int u = threadIdx.x; u < 512; u += 128) {
    int h = u >> 6, n = u & 63;
    size_t r0 = ((((size_t)0*16 + b*8 + h)*2 + 0)*5 + 4)*N_ + n0 + n;
    size_t r1 = ((((size_t)1*16 + b*8 + h)*2 + 0)*5 + 4)*N_ + n0 + n;
    invs[h][n] = 1.f / (part_g[r0] + part_g[r1]);
  }
  __syncthreads();

  const float* wrow = pw + (size_t)(c0 + l31)*IN_;
  bf16x8 afr[4];
  #pragma unroll
  for (int kk = 0; kk < 4; ++kk) {
    const float4* fp = reinterpret_cast<const float4*>(wrow + kk*16 + g*8);
    float4 f0 = fp[0], f1 = fp[1];
    uint4 u;
    u.x = pkbf(f0.x, f0.y); u.y = pkbf(f0.z, f0.w);
    u.z = pkbf(f1.x, f1.y); u.w = pkbf(f1.z, f1.w);
    afr[kk] = __builtin_bit_cast(bf16x8, u);
  }

  f32x16 acc;
  #pragma unroll
  for (int i = 0; i < 16; ++i) acc[i] = 0.f;
  #pragma unroll
  for (int kk = 0; kk < 4; ++kk) {
    int h = kk*2 + g;
    float iv = invs[h][wave*32 + l31];
    const float* p0 = part_g + (((size_t)0*16 + b*8 + h)*2)*5*N_ + nw + l31;
    const float* p1 = part_g + (((size_t)1*16 + b*8 + h)*2)*5*N_ + nw + l31;
    unsigned words[4];
    #pragma unroll
    for (int ep = 0; ep < 4; ++ep) {
      float vv[2];
      #pragma unroll
      for (int e2 = 0; e2 < 2; ++e2) {
        int d = ep*2 + e2;
        int gr = d >> 2, j = d & 3;
        size_t off = ((size_t)gr*5 + j)*N_;
        vv[e2] = (p0[off] + p1[off]) * iv;
      }
      words[ep] = pkbf(vv[0], vv[1]);
    }
    uint4 bu = make_uint4(words[0], words[1], words[2], words[3]);
    acc = __builtin_amdgcn_mfma_f32_32x32x16_bf16(afr[kk], __builtin_bit_cast(bf16x8, bu), acc, 0, 0, 0);
  }

  unsigned short* op = outc + ((size_t)b*C_ + c0)*N_ + nw + l31;
  #pragma unroll
  for (int reg = 0; reg < 16; ++reg) {
    int row = (reg & 3) + 8*(reg >> 2) + 4*g;
    __bf16 vb = (__bf16)acc[reg];
    op[(size_t)row*N_] = __builtin_bit_cast(unsigned short, vb);
  }

  // GN partials from fp32 accumulators
  float s4[4], q4[4];
  #pragma unroll
  for (int gl = 0; gl < 4; ++gl) {
    s4[gl] = acc[gl*4+0] + acc[gl*4+1] + acc[gl*4+2] + acc[gl*4+3];
    q4[gl] = acc[gl*4+0]*acc[gl*4+0] + acc[gl*4+1]*acc[gl*4+1]
           + acc[gl*4+2]*acc[gl*4+2] + acc[gl*4+3]*acc[gl*4+3];
  }
  #pragma unroll
  for (int gl = 0; gl < 4; ++gl) {
    #pragma unroll
    for (int off = 32; off > 0; off >>= 1) {
      s4[gl] += __shfl_xor(s4[gl], off);
      q4[gl] += __shfl_xor(q4[gl], off);
    }
  }
  __shared__ float red[2][4][2];
  if (lane == 0) {
    #pragma unroll
    for (int gl = 0; gl < 4; ++gl) { red[wave][gl][0] = s4[gl]; red[wave][gl][1] = q4[gl]; }
  }
  __syncthreads();
  if (threadIdx.x < 8) {
    int gl = threadIdx.x >> 1, which = threadIdx.x & 1;
    float v = red[0][gl][which] + red[1][gl][which];
    atomicAdd(&gst[((size_t)b*32 + ct*4 + gl)*2 + which], v);
  }
}

// K10: out = x + GN(outc_bf16)*gamma + beta, 8 elements/thread.
__global__ __launch_bounds__(256) void k_final(const float* __restrict__ x,
    const unsigned short* __restrict__ outc, const float* __restrict__ gst,
    const float* __restrict__ gng, const float* __restrict__ gnb, float* __restrict__ out) {
  int tid = blockIdx.x*256 + threadIdx.x;
  size_t idx = (size_t)tid * 8;
  int c = (int)((idx / N_) % C_);
  int b = (int)(idx / ((size_t)C_*N_));
  int g = c >> 3;
  float S  = gst[(b*32+g)*2];
  float SS = gst[(b*32+g)*2+1];
  const float invn = 1.f/(8.f*N_);
  float mu = S * invn;
  float var = SS * invn - mu*mu;
  float rs = rsqrtf(var + EPSF);
  float ga = gng[c], be = gnb[c];
  float4 xv0 = *reinterpret_cast<const float4*>(x + idx);
  float4 xv1 = *reinterpret_cast<const float4*>(x + idx + 4);
  uint4 ou = *reinterpret_cast<const uint4*>(outc + idx);
  float o[8];
  o[0] = bf2f((unsigned short)(ou.x & 0xffff)); o[1] = bf2f((unsigned short)(ou.x >> 16));
  o[2] = bf2f((unsigned short)(ou.y & 0xffff)); o[3] = bf2f((unsigned short)(ou.y >> 16));
  o[4] = bf2f((unsigned short)(ou.z & 0xffff)); o[5] = bf2f((unsigned short)(ou.z >> 16));
  o[6] = bf2f((unsigned short)(ou.w & 0xffff)); o[7] = bf2f((unsigned short)(ou.w >> 16));
  float4 r0, r1;
  r0.x = xv0.x + (o[0] - mu)*rs*ga + be;
  r0.y = xv0.y + (o[1] - mu)*rs*ga + be;
  r0.z = xv0.z + (o[2] - mu)*rs*ga + be;
  r0.w = xv0.w + (o[3] - mu)*rs*ga + be;
  r1.x = xv1.x + (o[4] - mu)*rs*ga + be;
  r1.y = xv1.y + (o[5] - mu)*rs*ga + be;
  r1.z = xv1.z + (o[6] - mu)*rs*ga + be;
  r1.w = xv1.w + (o[7] - mu)*rs*ga + be;
  *reinterpret_cast<float4*>(out + idx)     = r0;
  *reinterpret_cast<float4*>(out + idx + 4) = r1;
}

extern "C" void kernel_launch(void* const* d_in, const int* in_sizes, int n_in,
                              void* d_out, int out_size, void* d_ws, size_t ws_size,
                              hipStream_t stream) {
  const float* x   = (const float*)d_in[0];
  const float* gcw = (const float*)d_in[1];
  const float* bng = (const float*)d_in[2];
  const float* bnb = (const float*)d_in[3];
  const float* bnm = (const float*)d_in[4];
  const float* bnv = (const float*)d_in[5];
  const float* ghw = (const float*)d_in[6];
  const float* gww = (const float*)d_in[7];
  const float* piw = (const float*)d_in[8];
  const float* lng = (const float*)d_in[9];
  const float* lnb = (const float*)d_in[10];
  const float* wq  = (const float*)d_in[11];
  const float* wk  = (const float*)d_in[12];
  const float* wv  = (const float*)d_in[13];
  const float* pw  = (const float*)d_in[14];
  const float* gng = (const float*)d_in[15];
  const float* gnb = (const float*)d_in[16];
  float* ws  = (float*)d_ws;
  float* out = (float*)d_out;
  unsigned short* qt   = (unsigned short*)(ws + O_QT);
  unsigned short* kt   = (unsigned short*)(ws + O_KT);
  unsigned short* vt   = (unsigned short*)(ws + O_VT);
  unsigned short* vz   = (unsigned short*)(ws + O_VZ);
  unsigned short* outc = (unsigned short*)(ws + O_OUTC);

  k_pool<<<B_*C_, 256, 0, stream>>>(x, ws + O_POOL);
  k_gates2<<<B_*H_, 256, 0, stream>>>(gcw, ws+O_POOL, bng, bnb, bnm, bnv, ghw, gww, ws+O_GH, ws+O_GW);
  k_fused<<<B_*49, 256, 0, stream>>>(x, piw, lng, lnb, wq, wk, wv, ws+O_GH, ws+O_GW,
                                     qt, kt, vt, vz, ws+O_GST);
  k_attn9<<<16*98, 256, 0, stream>>>(qt, kt, vt, vz, ws+O_PART);
  k_proj3<<<B_*8*49, 128, 0, stream>>>(ws+O_PART, pw, outc, ws+O_GST);
  k_final<<<(B_*C_*N_)/(8*256), 256, 0, stream>>>(x, outc, ws+O_GST, gng, gnb, out);
}

// Round 16
// 78.112 us; speedup vs baseline: 1.0559x; 1.0281x over previous
//
#include <hip/hip_runtime.h>
#include <math.h>

#define EPSF 1e-5f

constexpr int B_ = 2, C_ = 256, H_ = 56, W_ = 56, N_ = 3136;
constexpr int MID_ = 32, L_ = 112, IN_ = 64, NH_ = 8;

typedef __attribute__((ext_vector_type(8))) __bf16 bf16x8;
typedef __attribute__((ext_vector_type(16))) float f32x16;

// workspace offsets (in floats; all multiples of 4 for 16B alignment)
constexpr size_t O_POOL = 0;
constexpr size_t O_GH   = O_POOL + (size_t)B_*C_*L_;             // ghT [b][H][C]
constexpr size_t O_GW   = O_GH   + (size_t)B_*C_*H_;             // gwT [b][W][C]
constexpr size_t O_QT   = O_GW   + (size_t)B_*C_*W_;             // bf16 [16bh][N][16]
constexpr size_t O_KT   = O_QT   + (size_t)B_*NH_*N_*16/2;
constexpr size_t O_VT   = O_KT   + (size_t)B_*NH_*N_*16/2;       // bf16 [16bh][16][N]
constexpr size_t O_VZ   = O_VT   + (size_t)B_*NH_*16*N_/2;       // bf16 zero row [N]
constexpr size_t O_OUTC = O_VZ   + N_/2;                          // bf16 [B][C][N]
constexpr size_t O_GST  = O_OUTC + (size_t)B_*C_*N_/2;           // fp32 [b*32+g][2] = {S, SS}
constexpr size_t O_PART = O_GST  + (size_t)B_*32*2;              // fp32 [2half][16bh][2g][5][N]

__device__ inline unsigned pkbf(float lo, float hi) {
  __bf16 a = (__bf16)lo, c = (__bf16)hi;
  return (unsigned)__builtin_bit_cast(unsigned short, a)
       | ((unsigned)__builtin_bit_cast(unsigned short, c) << 16);
}

__device__ inline float bf2f(unsigned short u) {
  unsigned v = (unsigned)u << 16;
  return __builtin_bit_cast(float, v);
}

__device__ inline float fast_exp2(float x) {
#if __has_builtin(__builtin_amdgcn_exp2f)
  return __builtin_amdgcn_exp2f(x);
#else
  float r; asm("v_exp_f32 %0, %1" : "=v"(r) : "v"(x)); return r;
#endif
}

__device__ inline void plane32_swap(unsigned &a, unsigned &b) {
#if __has_builtin(__builtin_amdgcn_permlane32_swap)
  typedef unsigned uv2 __attribute__((ext_vector_type(2)));
  uv2 r = __builtin_amdgcn_permlane32_swap(a, b, false, false);
  a = r.x; b = r.y;
#else
  asm volatile("v_permlane32_swap_b32 %0, %1" : "+v"(a), "+v"(b));
#endif
}

// K1: h_pool / w_pool. one block per (b,c). float4 staging, 224-thread reduce.
__global__ __launch_bounds__(256) void k_pool(const float* __restrict__ x, float* __restrict__ pool) {
  int bc = blockIdx.x;
  const float4* xp4 = reinterpret_cast<const float4*>(x + (size_t)bc * N_);
  __shared__ float tile[N_];
  float4* t4 = reinterpret_cast<float4*>(tile);
  for (int i = threadIdx.x; i < N_/4; i += 256) t4[i] = xp4[i];
  __syncthreads();
  int t = threadIdx.x;
  if (t < 224) {
    int o = t >> 1, half = t & 1;
    float r = 0.f;
    if (o < 56) {
      const float* row = tile + o*W_ + half*28;
      #pragma unroll 7
      for (int j = 0; j < 28; ++j) r += row[j];
    } else {
      const float* col = tile + (half*28)*W_ + (o - 56);
      #pragma unroll 7
      for (int j = 0; j < 28; ++j) r += col[j*W_];
    }
    r += __shfl_xor(r, 1);
    if (half == 0) pool[(size_t)bc*L_ + o] = r * (1.f/56.f);
  }
}

// K3': gates with inline cat recompute. grid = B*H = 112 blocks.
__global__ __launch_bounds__(256) void k_gates2(const float* __restrict__ gcw, const float* __restrict__ pool,
    const float* __restrict__ bng, const float* __restrict__ bnb,
    const float* __restrict__ bnm, const float* __restrict__ bnv,
    const float* __restrict__ ghw, const float* __restrict__ gww,
    float* __restrict__ ghT, float* __restrict__ gwT) {
  int b = blockIdx.x / H_;
  int p = blockIdx.x % H_;
  __shared__ float cat_s[2][MID_];
  int t = threadIdx.x;
  {
    int out = t >> 2, sub = t & 3;
    int m = out & 31, which = out >> 5;
    int l = p + which*H_;
    const float* pp = pool + (size_t)b*C_*L_ + l;
    const float* wp = gcw + (size_t)m*C_ + sub*64;
    float s = 0.f;
    #pragma unroll 16
    for (int c = 0; c < 64; ++c) s += wp[c] * pp[(size_t)(sub*64 + c)*L_];
    s += __shfl_xor(s, 1); s += __shfl_xor(s, 2);
    if (sub == 0) {
      float xn = (s - bnm[m]) * rsqrtf(bnv[m] + EPSF) * bng[m] + bnb[m];
      cat_s[which][m] = xn * fminf(fmaxf(xn + 3.f, 0.f), 6.f) * (1.f/6.f);
    }
  }
  __syncthreads();
  int c = t;
  float sh = 0.f, sw = 0.f;
  #pragma unroll 8
  for (int m = 0; m < MID_; ++m) {
    sh += ghw[c*MID_ + m] * cat_s[0][m];
    sw += gww[c*MID_ + m] * cat_s[1][m];
  }
  ghT[((size_t)b*H_ + p)*C_ + c] = 1.f/(1.f + expf(-sh));
  gwT[((size_t)b*W_ + p)*C_ + c] = 1.f/(1.f + expf(-sw));
}

// K5: fused bias + proj_in GEMM (MFMA) + LayerNorm + QKV GEMM (MFMA) + layout packing.
// Also zeroes gst (block 0).
__global__ __launch_bounds__(256) void k_fused(const float* __restrict__ x,
    const float* __restrict__ piw, const float* __restrict__ lng, const float* __restrict__ lnb,
    const float* __restrict__ wq, const float* __restrict__ wk, const float* __restrict__ wv,
    const float* __restrict__ ghT, const float* __restrict__ gwT,
    unsigned short* __restrict__ qt, unsigned short* __restrict__ kt,
    unsigned short* __restrict__ vt, unsigned short* __restrict__ vz,
    float* __restrict__ gst) {
  __shared__ __align__(16) unsigned short sT[64][72];
  __shared__ float ps[2][2][64][2];
  __shared__ float lg[64], lb[64];
  __shared__ float bias_s[64];
  int b = blockIdx.x / 49, n0 = (blockIdx.x % 49) * 64;
  int tid = threadIdx.x;
  int wv_ = tid >> 6, lane = tid & 63;
  int m = wv_ & 1, nh = wv_ >> 1, l31 = lane & 31, g = lane >> 5;
  int nloc = nh*32 + l31;
  int nglob = n0 + nloc;
  const float QS = 0.35355339059327373f * 1.4426950408889634f;  // scale * log2(e)

  if (tid < 64) { lg[tid] = lng[tid]; lb[tid] = lnb[tid]; }
  if (blockIdx.x == 0 && tid < B_*32*2) gst[tid] = 0.f;

  {
    int px = tid >> 2, sub = tid & 3;
    int n = n0 + px;
    int h = n / W_, w = n % W_;
    const float4* gh4 = reinterpret_cast<const float4*>(ghT + ((size_t)b*H_ + h)*C_ + sub*64);
    const float4* gw4 = reinterpret_cast<const float4*>(gwT + ((size_t)b*W_ + w)*C_ + sub*64);
    float s = 0.f;
    #pragma unroll
    for (int i = 0; i < 16; ++i) {
      float4 a = gh4[i], c2 = gw4[i];
      s += a.x*c2.x + a.y*c2.y + a.z*c2.z + a.w*c2.w;
    }
    s += __shfl_xor(s, 1); s += __shfl_xor(s, 2);
    if (sub == 0)
      bias_s[px] = fmaxf(logf(s * (1.f/C_)), -5.f) * 1.4426950408889634f;
  }
  __syncthreads();

  for (int u = tid; u < 512; u += 256) {
    int h = u >> 6, n = u & 63;
    size_t base = ((size_t)(b*NH_ + h)*N_ + n0 + n)*16;
    *reinterpret_cast<uint4*>(qt + base + 8) = make_uint4(0x3F803F80u, 0u, 0u, 0u);
    float bv = bias_s[n];
    __bf16 bhi = (__bf16)bv; float blo = bv - (float)bhi;
    *reinterpret_cast<uint4*>(kt + base + 8) = make_uint4(pkbf((float)bhi, blo), 0u, 0u, 0u);
  }
  for (int u = tid; u < 512; u += 256) {
    int rr = u >> 3, chunk = u & 7;
    int h = rr >> 3, r = 8 + (rr & 7);
    unsigned val = (r == 8 || r == 12) ? 0x3F803F80u : 0u;
    *reinterpret_cast<uint4*>(vt + ((size_t)(b*NH_+h)*16 + r)*N_ + n0 + chunk*8)
        = make_uint4(val, val, val, val);
  }
  if (b == 0 && tid < 8)
    *reinterpret_cast<uint4*>(vz + n0 + tid*8) = make_uint4(0u, 0u, 0u, 0u);

  // GEMM1: seq_pre[i][n] = sum_c piw[i][c] * x[b][c][n]
  const float* arow = piw + (size_t)(32*m + l31)*C_;
  const float* xcol = x + (size_t)b*C_*N_ + nglob;
  f32x16 acc;
  #pragma unroll
  for (int i = 0; i < 16; ++i) acc[i] = 0.f;
  #pragma unroll 4
  for (int kk = 0; kk < 16; ++kk) {
    const float4* ap = reinterpret_cast<const float4*>(arow + kk*16 + g*8);
    float4 a0 = ap[0], a1 = ap[1];
    uint4 au;
    au.x = pkbf(a0.x, a0.y); au.y = pkbf(a0.z, a0.w);
    au.z = pkbf(a1.x, a1.y); au.w = pkbf(a1.z, a1.w);
    float bvl[8];
    #pragma unroll
    for (int e = 0; e < 8; ++e) bvl[e] = xcol[(size_t)(kk*16 + g*8 + e)*N_];
    uint4 bu;
    bu.x = pkbf(bvl[0], bvl[1]); bu.y = pkbf(bvl[2], bvl[3]);
    bu.z = pkbf(bvl[4], bvl[5]); bu.w = pkbf(bvl[6], bvl[7]);
    acc = __builtin_amdgcn_mfma_f32_32x32x16_bf16(
        __builtin_bit_cast(bf16x8, au), __builtin_bit_cast(bf16x8, bu), acc, 0, 0, 0);
  }

  float s = 0.f, ss = 0.f;
  #pragma unroll
  for (int i = 0; i < 16; ++i) { s += acc[i]; ss += acc[i]*acc[i]; }
  ps[m][g][nloc][0] = s; ps[m][g][nloc][1] = ss;
  __syncthreads();
  float S  = ps[0][0][nloc][0] + ps[0][1][nloc][0] + ps[1][0][nloc][0] + ps[1][1][nloc][0];
  float SS = ps[0][0][nloc][1] + ps[0][1][nloc][1] + ps[1][0][nloc][1] + ps[1][1][nloc][1];
  float mu = S * (1.f/IN_);
  float var = SS * (1.f/IN_) - mu*mu;
  float rsd = rsqrtf(var + EPSF);

  #pragma unroll
  for (int cg = 0; cg < 4; ++cg) {
    int jb = 8*cg + 4*g + 32*m;
    float v0 = (acc[cg*4+0]-mu)*rsd*lg[jb+0] + lb[jb+0];
    float v1 = (acc[cg*4+1]-mu)*rsd*lg[jb+1] + lb[jb+1];
    float v2 = (acc[cg*4+2]-mu)*rsd*lg[jb+2] + lb[jb+2];
    float v3 = (acc[cg*4+3]-mu)*rsd*lg[jb+3] + lb[jb+3];
    uint2 w; w.x = pkbf(v0, v1); w.y = pkbf(v2, v3);
    *reinterpret_cast<uint2*>(&sT[nloc][jb]) = w;
  }
  __syncthreads();

  // GEMM2: q/k/v[i][n] = sum_j w[i][j] * seq[n][j]
  f32x16 aq, ak, av;
  #pragma unroll
  for (int i = 0; i < 16; ++i) { aq[i] = 0.f; ak[i] = 0.f; av[i] = 0.f; }
  const float* qrw = wq + (size_t)(32*m + l31)*IN_;
  const float* krw = wk + (size_t)(32*m + l31)*IN_;
  const float* vrw = wv + (size_t)(32*m + l31)*IN_;
  #pragma unroll
  for (int kk = 0; kk < 4; ++kk) {
    bf16x8 bfr = __builtin_bit_cast(bf16x8,
        *reinterpret_cast<const uint4*>(&sT[nloc][kk*16 + g*8]));
    auto ldA = [&](const float* wrow) {
      const float4* fp = reinterpret_cast<const float4*>(wrow + kk*16 + g*8);
      float4 f0 = fp[0], f1 = fp[1];
      uint4 u;
      u.x = pkbf(f0.x, f0.y); u.y = pkbf(f0.z, f0.w);
      u.z = pkbf(f1.x, f1.y); u.w = pkbf(f1.z, f1.w);
      return __builtin_bit_cast(bf16x8, u);
    };
    aq = __builtin_amdgcn_mfma_f32_32x32x16_bf16(ldA(qrw), bfr, aq, 0, 0, 0);
    ak = __builtin_amdgcn_mfma_f32_32x32x16_bf16(ldA(krw), bfr, ak, 0, 0, 0);
    av = __builtin_amdgcn_mfma_f32_32x32x16_bf16(ldA(vrw), bfr, av, 0, 0, 0);
  }

  #pragma unroll
  for (int cg = 0; cg < 4; ++cg) {
    int h = 4*m + cg, d0 = 4*g;
    size_t rb = ((size_t)(b*NH_ + h)*N_ + nglob)*16 + d0;
    uint2 wqv;
    wqv.x = pkbf(aq[cg*4+0]*QS, aq[cg*4+1]*QS);
    wqv.y = pkbf(aq[cg*4+2]*QS, aq[cg*4+3]*QS);
    *reinterpret_cast<uint2*>(qt + rb) = wqv;
    uint2 wkv;
    wkv.x = pkbf(ak[cg*4+0], ak[cg*4+1]);
    wkv.y = pkbf(ak[cg*4+2], ak[cg*4+3]);
    *reinterpret_cast<uint2*>(kt + rb) = wkv;
    unsigned r0 = pkbf(av[cg*4+0], av[cg*4+1]);
    unsigned r1 = pkbf(av[cg*4+2], av[cg*4+3]);
    size_t vb0 = ((size_t)(b*NH_+h)*16 + d0)*N_ + nglob;
    vt[vb0]                = (unsigned short)r0;
    vt[vb0 + N_]           = (unsigned short)(r0 >> 16);
    vt[vb0 + 2*(size_t)N_] = (unsigned short)r1;
    vt[vb0 + 3*(size_t)N_] = (unsigned short)(r1 >> 16);
  }
}

// K7: MFMA flash attention v9: 2-stage score pipeline (unchanged from R14, no setprio).
__global__ __launch_bounds__(256, 3) void k_attn9(const unsigned short* __restrict__ qt,
    const unsigned short* __restrict__ kt, const unsigned short* __restrict__ vt,
    const unsigned short* __restrict__ vz, float* __restrict__ part_g) {
  int tid = threadIdx.x;
  int lane = tid & 63, kh = tid >> 6;
  int l31 = lane & 31, g = lane >> 5;
  int bh = blockIdx.x & 15;
  int rest = blockIdx.x >> 4;          // 0..97
  int qti = rest >> 1, half = rest & 1;
  int qbase = qti * 64;

  bf16x8 qfA = __builtin_bit_cast(bf16x8,
      *reinterpret_cast<const uint4*>(qt + ((size_t)bh*N_ + qbase + l31)*16 + g*8));
  bf16x8 qfB = __builtin_bit_cast(bf16x8,
      *reinterpret_cast<const uint4*>(qt + ((size_t)bh*N_ + qbase + 32 + l31)*16 + g*8));
  f32x16 zf, accA, accB;
  #pragma unroll
  for (int i = 0; i < 16; ++i) { zf[i] = 0.f; accA[i] = 0.f; accB[i] = 0.f; }
  const unsigned short* krow = kt + (size_t)bh*N_*16 + g*8;
  const unsigned short* vbase = (l31 < 16) ? (vt + ((size_t)bh*16 + l31)*(size_t)N_) : vz;

  auto ld = [&](const unsigned short* p) {
    return __builtin_bit_cast(bf16x8, *reinterpret_cast<const uint4*>(p));
  };
  auto halfstep = [&](const f32x16& sa, f32x16& acc, bf16x8 v1, bf16x8 v2) {
    float p[16];
    #pragma unroll
    for (int r = 0; r < 16; ++r) p[r] = fast_exp2(sa[r]);
    unsigned u01 = pkbf(p[0],p[1]),  u23 = pkbf(p[2],p[3]);
    unsigned u45 = pkbf(p[4],p[5]),  u67 = pkbf(p[6],p[7]);
    unsigned u89 = pkbf(p[8],p[9]),  uab = pkbf(p[10],p[11]);
    unsigned ucd = pkbf(p[12],p[13]), uef = pkbf(p[14],p[15]);
    plane32_swap(u01, u45);
    plane32_swap(u23, u67);
    plane32_swap(u89, ucd);
    plane32_swap(uab, uef);
    bf16x8 pf1 = __builtin_bit_cast(bf16x8, make_uint4(u01, u23, u45, u67));
    bf16x8 pf2 = __builtin_bit_cast(bf16x8, make_uint4(u89, uab, ucd, uef));
    acc = __builtin_amdgcn_mfma_f32_32x32x16_bf16(v1, pf1, acc, 0, 0, 0);
    acc = __builtin_amdgcn_mfma_f32_32x32x16_bf16(v2, pf2, acc, 0, 0, 0);
  };

  int tb0 = (half*49 + kh*12) * 32;
  const unsigned short* kp  = krow  + (size_t)(tb0 + l31)*16;   // +512 ushorts/tile
  const unsigned short* vp1 = vbase + tb0 + g*8;                // +32 ushorts/tile
  const unsigned short* vp2 = vp1 + 16;

  // prologue: tiles 0,1
  bf16x8 kf0  = ld(kp);
  bf16x8 v1_0 = ld(vp1),      v2_0 = ld(vp2);
  bf16x8 kf1  = ld(kp + 512);
  bf16x8 v1_1 = ld(vp1 + 32), v2_1 = ld(vp2 + 32);
  f32x16 sA0 = __builtin_amdgcn_mfma_f32_32x32x16_bf16(kf0, qfA, zf, 0, 0, 0);
  f32x16 sB0 = __builtin_amdgcn_mfma_f32_32x32x16_bf16(kf0, qfB, zf, 0, 0, 0);

  #pragma unroll 2
  for (int j = 0; j < 10; ++j) {
    bf16x8 kfn = ld(kp  + (size_t)(j+2)*512);
    bf16x8 v1n = ld(vp1 + (j+2)*32);
    bf16x8 v2n = ld(vp2 + (j+2)*32);
    f32x16 sA1 = __builtin_amdgcn_mfma_f32_32x32x16_bf16(kf1, qfA, zf, 0, 0, 0);
    f32x16 sB1 = __builtin_amdgcn_mfma_f32_32x32x16_bf16(kf1, qfB, zf, 0, 0, 0);
    halfstep(sA0, accA, v1_0, v2_0);
    halfstep(sB0, accB, v1_0, v2_0);
    sA0 = sA1; sB0 = sB1;
    kf1 = kfn;
    v1_0 = v1_1; v2_0 = v2_1; v1_1 = v1n; v2_1 = v2n;
  }
  {
    f32x16 sA1 = __builtin_amdgcn_mfma_f32_32x32x16_bf16(kf1, qfA, zf, 0, 0, 0);
    f32x16 sB1 = __builtin_amdgcn_mfma_f32_32x32x16_bf16(kf1, qfB, zf, 0, 0, 0);
    halfstep(sA0, accA, v1_0, v2_0);
    halfstep(sB0, accB, v1_0, v2_0);
    halfstep(sA1, accA, v1_1, v2_1);
    halfstep(sB1, accB, v1_1, v2_1);
  }
  if (kh == 0) {
    int tb = (half*49 + 48) * 32;
    bf16x8 kf = ld(krow + (size_t)(tb + l31)*16);
    bf16x8 v1 = ld(vbase + tb + g*8);
    bf16x8 v2 = ld(vbase + tb + 16 + g*8);
    f32x16 sA = __builtin_amdgcn_mfma_f32_32x32x16_bf16(kf, qfA, zf, 0, 0, 0);
    f32x16 sB = __builtin_amdgcn_mfma_f32_32x32x16_bf16(kf, qfB, zf, 0, 0, 0);
    halfstep(sA, accA, v1, v2);
    halfstep(sB, accB, v1, v2);
  }

  __shared__ float part[3][2][64][5];
  if (kh > 0) {
    #pragma unroll
    for (int j = 0; j < 5; ++j) {
      part[kh-1][0][lane][j] = accA[j];
      part[kh-1][1][lane][j] = accB[j];
    }
  }
  __syncthreads();
  if (kh == 0) {
    float rA[5], rB[5];
    #pragma unroll
    for (int j = 0; j < 5; ++j) { rA[j] = accA[j]; rB[j] = accB[j]; }
    #pragma unroll
    for (int c = 0; c < 3; ++c) {
      #pragma unroll
      for (int j = 0; j < 5; ++j) {
        rA[j] += part[c][0][lane][j];
        rB[j] += part[c][1][lane][j];
      }
    }
    float* pg = part_g + ((((size_t)half*16 + bh)*2 + g)*5)*N_ + qbase + l31;
    #pragma unroll
    for (int j = 0; j < 5; ++j) {
      pg[(size_t)j*N_]      = rA[j];
      pg[(size_t)j*N_ + 32] = rB[j];
    }
  }
}

// K8: proj_out MFMA GEMM reading attention partials directly; outc stored bf16;
// GN partial sums. Corrected bijective XCD swizzle for nwg=784=8*98:
// wg = (p&7)*98 + (p>>3); the 8 c-tiles of each (b,nb) are consecutive logical wg
// -> same XCD; per-XCD part_g working set ~2 MB (fits 4 MB L2).
__global__ __launch_bounds__(128) void k_proj3(const float* __restrict__ part_g,
    const float* __restrict__ pw, unsigned short* __restrict__ outc, float* __restrict__ gst) {
  int wg = (blockIdx.x & 7) * 98 + (blockIdx.x >> 3);   // bijective on [0,784)
  int ct = wg & 7, nb = (wg >> 3) % 49, b = wg / 392;
  int wave = threadIdx.x >> 6, lane = threadIdx.x & 63;
  int l31 = lane & 31, g = lane >> 5;
  int n0 = nb*64, c0 = ct*32;
  int nw = n0 + wave*32;

  __shared__ float invs[8][64];
  for (int u = threadIdx.x; u < 512; u += 128) {
    int h = u >> 6, n = u & 63;
    size_t r0 = ((((size_t)0*16 + b*8 + h)*2 + 0)*5 + 4)*N_ + n0 + n;
    size_t r1 = ((((size_t)1*16 + b*8 + h)*2 + 0)*5 + 4)*N_ + n0 + n;
    invs[h][n] = 1.f / (part_g[r0] + part_g[r1]);
  }
  __syncthreads();

  const float* wrow = pw + (size_t)(c0 + l31)*IN_;
  bf16x8 afr[4];
  #pragma unroll
  for (int kk = 0; kk < 4; ++kk) {
    const float4* fp = reinterpret_cast<const float4*>(wrow + kk*16 + g*8);
    float4 f0 = fp[0], f1 = fp[1];
    uint4 u;
    u.x = pkbf(f0.x, f0.y); u.y = pkbf(f0.z, f0.w);
    u.z = pkbf(f1.x, f1.y); u.w = pkbf(f1.z, f1.w);
    afr[kk] = __builtin_bit_cast(bf16x8, u);
  }

  f32x16 acc;
  #pragma unroll
  for (int i = 0; i < 16; ++i) acc[i] = 0.f;
  #pragma unroll
  for (int kk = 0; kk < 4; ++kk) {
    int h = kk*2 + g;
    float iv = invs[h][wave*32 + l31];
    const float* p0 = part_g + (((size_t)0*16 + b*8 + h)*2)*5*N_ + nw + l31;
    const float* p1 = part_g + (((size_t)1*16 + b*8 + h)*2)*5*N_ + nw + l31;
    unsigned words[4];
    #pragma unroll
    for (int ep = 0; ep < 4; ++ep) {
      float vv[2];
      #pragma unroll
      for (int e2 = 0; e2 < 2; ++e2) {
        int d = ep*2 + e2;
        int gr = d >> 2, j = d & 3;
        size_t off = ((size_t)gr*5 + j)*N_;
        vv[e2] = (p0[off] + p1[off]) * iv;
      }
      words[ep] = pkbf(vv[0], vv[1]);
    }
    uint4 bu = make_uint4(words[0], words[1], words[2], words[3]);
    acc = __builtin_amdgcn_mfma_f32_32x32x16_bf16(afr[kk], __builtin_bit_cast(bf16x8, bu), acc, 0, 0, 0);
  }

  unsigned short* op = outc + ((size_t)b*C_ + c0)*N_ + nw + l31;
  #pragma unroll
  for (int reg = 0; reg < 16; ++reg) {
    int row = (reg & 3) + 8*(reg >> 2) + 4*g;
    __bf16 vb = (__bf16)acc[reg];
    op[(size_t)row*N_] = __builtin_bit_cast(unsigned short, vb);
  }

  // GN partials from fp32 accumulators
  float s4[4], q4[4];
  #pragma unroll
  for (int gl = 0; gl < 4; ++gl) {
    s4[gl] = acc[gl*4+0] + acc[gl*4+1] + acc[gl*4+2] + acc[gl*4+3];
    q4[gl] = acc[gl*4+0]*acc[gl*4+0] + acc[gl*4+1]*acc[gl*4+1]
           + acc[gl*4+2]*acc[gl*4+2] + acc[gl*4+3]*acc[gl*4+3];
  }
  #pragma unroll
  for (int gl = 0; gl < 4; ++gl) {
    #pragma unroll
    for (int off = 32; off > 0; off >>= 1) {
      s4[gl] += __shfl_xor(s4[gl], off);
      q4[gl] += __shfl_xor(q4[gl], off);
    }
  }
  __shared__ float red[2][4][2];
  if (lane == 0) {
    #pragma unroll
    for (int gl = 0; gl < 4; ++gl) { red[wave][gl][0] = s4[gl]; red[wave][gl][1] = q4[gl]; }
  }
  __syncthreads();
  if (threadIdx.x < 8) {
    int gl = threadIdx.x >> 1, which = threadIdx.x & 1;
    float v = red[0][gl][which] + red[1][gl][which];
    atomicAdd(&gst[((size_t)b*32 + ct*4 + gl)*2 + which], v);
  }
}

// K10: out = x + GN(outc_bf16)*gamma + beta, 8 elements/thread.
__global__ __launch_bounds__(256) void k_final(const float* __restrict__ x,
    const unsigned short* __restrict__ outc, const float* __restrict__ gst,
    const float* __restrict__ gng, const float* __restrict__ gnb, float* __restrict__ out) {
  int tid = blockIdx.x*256 + threadIdx.x;
  size_t idx = (size_t)tid * 8;
  int c = (int)((idx / N_) % C_);
  int b = (int)(idx / ((size_t)C_*N_));
  int g = c >> 3;
  float S  = gst[(b*32+g)*2];
  float SS = gst[(b*32+g)*2+1];
  const float invn = 1.f/(8.f*N_);
  float mu = S * invn;
  float var = SS * invn - mu*mu;
  float rs = rsqrtf(var + EPSF);
  float ga = gng[c], be = gnb[c];
  float4 xv0 = *reinterpret_cast<const float4*>(x + idx);
  float4 xv1 = *reinterpret_cast<const float4*>(x + idx + 4);
  uint4 ou = *reinterpret_cast<const uint4*>(outc + idx);
  float o[8];
  o[0] = bf2f((unsigned short)(ou.x & 0xffff)); o[1] = bf2f((unsigned short)(ou.x >> 16));
  o[2] = bf2f((unsigned short)(ou.y & 0xffff)); o[3] = bf2f((unsigned short)(ou.y >> 16));
  o[4] = bf2f((unsigned short)(ou.z & 0xffff)); o[5] = bf2f((unsigned short)(ou.z >> 16));
  o[6] = bf2f((unsigned short)(ou.w & 0xffff)); o[7] = bf2f((unsigned short)(ou.w >> 16));
  float4 r0, r1;
  r0.x = xv0.x + (o[0] - mu)*rs*ga + be;
  r0.y = xv0.y + (o[1] - mu)*rs*ga + be;
  r0.z = xv0.z + (o[2] - mu)*rs*ga + be;
  r0.w = xv0.w + (o[3] - mu)*rs*ga + be;
  r1.x = xv1.x + (o[4] - mu)*rs*ga + be;
  r1.y = xv1.y + (o[5] - mu)*rs*ga + be;
  r1.z = xv1.z + (o[6] - mu)*rs*ga + be;
  r1.w = xv1.w + (o[7] - mu)*rs*ga + be;
  *reinterpret_cast<float4*>(out + idx)     = r0;
  *reinterpret_cast<float4*>(out + idx + 4) = r1;
}

extern "C" void kernel_launch(void* const* d_in, const int* in_sizes, int n_in,
                              void* d_out, int out_size, void* d_ws, size_t ws_size,
                              hipStream_t stream) {
  const float* x   = (const float*)d_in[0];
  const float* gcw = (const float*)d_in[1];
  const float* bng = (const float*)d_in[2];
  const float* bnb = (const float*)d_in[3];
  const float* bnm = (const float*)d_in[4];
  const float* bnv = (const float*)d_in[5];
  const float* ghw = (const float*)d_in[6];
  const float* gww = (const float*)d_in[7];
  const float* piw = (const float*)d_in[8];
  const float* lng = (const float*)d_in[9];
  const float* lnb = (const float*)d_in[10];
  const float* wq  = (const float*)d_in[11];
  const float* wk  = (const float*)d_in[12];
  const float* wv  = (const float*)d_in[13];
  const float* pw  = (const float*)d_in[14];
  const float* gng = (const float*)d_in[15];
  const float* gnb = (const float*)d_in[16];
  float* ws  = (float*)d_ws;
  float* out = (float*)d_out;
  unsigned short* qt   = (unsigned short*)(ws + O_QT);
  unsigned short* kt   = (unsigned short*)(ws + O_KT);
  unsigned short* vt   = (unsigned short*)(ws + O_VT);
  unsigned short* vz   = (unsigned short*)(ws + O_VZ);
  unsigned short* outc = (unsigned short*)(ws + O_OUTC);

  k_pool<<<B_*C_, 256, 0, stream>>>(x, ws + O_POOL);
  k_gates2<<<B_*H_, 256, 0, stream>>>(gcw, ws+O_POOL, bng, bnb, bnm, bnv, ghw, gww, ws+O_GH, ws+O_GW);
  k_fused<<<B_*49, 256, 0, stream>>>(x, piw, lng, lnb, wq, wk, wv, ws+O_GH, ws+O_GW,
                                     qt, kt, vt, vz, ws+O_GST);
  k_attn9<<<16*98, 256, 0, stream>>>(qt, kt, vt, vz, ws+O_PART);
  k_proj3<<<B_*8*49, 128, 0, stream>>>(ws+O_PART, pw, outc, ws+O_GST);
  k_final<<<(B_*C_*N_)/(8*256), 256, 0, stream>>>(x, outc, ws+O_GST, gng, gnb, out);
}